// Round 1
// baseline (763.742 us; speedup 1.0000x reference)
//
#include <hip/hip_runtime.h>
#include <hip/hip_bf16.h>
#include <math.h>

// Problem constants
#define Hh 192
#define Ww 192
#define HWp (Hh*Ww)          // 36864
#define Bb 2
#define Cch 64
#define DI 128
#define NWX 24               // windows per row
#define WPB 576              // windows per batch
#define NW  1152             // total windows
#define DS 16
#define SHIFT 4

// ------------------- K1: NCHW -> NHWC transpose -------------------
__global__ __launch_bounds__(256) void k_transpose(const float* __restrict__ x, float* __restrict__ xT){
  __shared__ float t[64][65];
  int b   = blockIdx.x / WPB;
  int hw0 = (blockIdx.x % WPB) * 64;
  int lane = threadIdx.x & 63, grp = threadIdx.x >> 6;
  const float* xb = x + (size_t)b * Cch * HWp;
  #pragma unroll
  for (int r = 0; r < 64; r += 4) {
    int c = r + grp;
    t[c][lane] = xb[(size_t)c * HWp + hw0 + lane];
  }
  __syncthreads();
  float* xo = xT + ((size_t)b * HWp + hw0) * 64;
  #pragma unroll
  for (int r = 0; r < 64; r += 4) {
    int hwl = r + grp;
    xo[(size_t)hwl * 64 + lane] = t[lane][hwl];
  }
}

// ------------------- K2: shift + LN1 + in_proj + mask -------------------
__global__ __launch_bounds__(256) void k_stage1(
    const float* __restrict__ xT, const float* __restrict__ g1, const float* __restrict__ b1,
    const float* __restrict__ in_w, const float* __restrict__ in_b,
    float* __restrict__ Xin, float* __restrict__ Zb){
  __shared__ __align__(16) float xs[64][68];
  int n = blockIdx.x;
  int b = n / WPB, wi = n % WPB;
  int wy = wi / NWX, wx = wi % NWX;
  int tid = threadIdx.x;
  int l = tid >> 2, q = tid & 3;       // token l (0..63), quarter q
  int iy = l >> 3, ix = l & 7;
  int h = wy*8 + iy, w = wx*8 + ix;    // shifted-space coords
  int hs = h + SHIFT; if (hs >= Hh) hs -= Hh;
  int ws2 = w + SHIFT; if (ws2 >= Ww) ws2 -= Ww;
  const float* src = xT + ((size_t)b*HWp + (size_t)hs*Ww + ws2) * 64 + q*16;
  float v[16];
  float s1 = 0.f, s2 = 0.f;
  #pragma unroll
  for (int k = 0; k < 4; k++) {
    float4 f = *reinterpret_cast<const float4*>(src + k*4);
    v[k*4+0]=f.x; v[k*4+1]=f.y; v[k*4+2]=f.z; v[k*4+3]=f.w;
  }
  #pragma unroll
  for (int i = 0; i < 16; i++) { s1 += v[i]; s2 += v[i]*v[i]; }
  s1 += __shfl_xor(s1, 1); s2 += __shfl_xor(s2, 1);
  s1 += __shfl_xor(s1, 2); s2 += __shfl_xor(s2, 2);
  float mu = s1 * (1.f/64.f);
  float var = s2 * (1.f/64.f) - mu*mu;
  float rstd = rsqrtf(var + 1e-5f);
  #pragma unroll
  for (int i = 0; i < 16; i++) {
    int c = q*16 + i;
    xs[l][c] = (v[i]-mu)*rstd*g1[c] + b1[c];
  }
  __syncthreads();
  // GEMM: 64 tokens x (64 -> 256). thread owns output column o = tid.
  int o = tid;
  float bias = in_b[o];
  for (int lc = 0; lc < 64; lc += 8) {
    float acc[8] = {0.f,0.f,0.f,0.f,0.f,0.f,0.f,0.f};
    for (int c = 0; c < 64; c++) {
      float wv = in_w[c*256 + o];
      #pragma unroll
      for (int j = 0; j < 8; j++) acc[j] += xs[lc+j][c] * wv;
    }
    #pragma unroll
    for (int j = 0; j < 8; j++) {
      int l2 = lc + j;
      float val = acc[j] + bias;
      int hh = wy*8 + (l2>>3), ww2 = wx*8 + (l2&7);
      if (o < 128) {
        float m = (hh < Hh-SHIFT && ww2 < Ww-SHIFT) ? 1.f : 0.f;
        Xin[((size_t)n*64 + l2)*128 + o] = val * m;
      } else {
        Zb[((size_t)n*64 + l2)*128 + (o-128)] = val;
      }
    }
  }
}

// ------------------- K3: conv1d + xproj + dt + scan + gate + out_proj -------------------
__global__ __launch_bounds__(128) void k_scan(
    const float* __restrict__ Xin, const float* __restrict__ Zb,
    const float* __restrict__ conv_w, const float* __restrict__ conv_b,
    const float* __restrict__ xproj_w,
    const float* __restrict__ dt_w, const float* __restrict__ dt_b,
    const float* __restrict__ A_log, const float* __restrict__ Dp,
    const float* __restrict__ out_w, const float* __restrict__ out_b,
    float* __restrict__ outw){
  __shared__ float xc_s[16][129];
  __shared__ float dbc_s[16][40];
  int n = blockIdx.x;
  int d = threadIdx.x; // 0..127
  float cw0 = conv_w[d], cw1 = conv_w[128+d], cw2 = conv_w[256+d], cw3 = conv_w[384+d];
  float cb  = conv_b[d];
  float a[16];
  #pragma unroll
  for (int s = 0; s < 16; s++) a[s] = -expf(A_log[d*16+s]);
  float dtb  = dt_b[d];
  float dtw0 = dt_w[d], dtw1 = dt_w[128+d], dtw2 = dt_w[256+d], dtw3 = dt_w[384+d];
  float Dd = Dp[d];
  float h[16];
  #pragma unroll
  for (int s = 0; s < 16; s++) h[s] = 0.f;
  float p1 = 0.f, p2 = 0.f, p3 = 0.f;  // conv history x[t-1], x[t-2], x[t-3]
  const float* Xn = Xin + (size_t)n*64*128;
  const float* Zn = Zb  + (size_t)n*64*128;
  float* On = outw + (size_t)n*64*64;
  int ob  = threadIdx.x & 63;
  int oth = threadIdx.x >> 6;
  float outb = out_b[ob];

  for (int ch = 0; ch < 4; ch++) {
    int t0 = ch*16;
    float zreg[16];
    // load + causal conv(K=4) + silu -> xc_s
    #pragma unroll
    for (int i = 0; i < 16; i++) {
      float xv = Xn[(size_t)(t0+i)*128 + d];
      zreg[i]  = Zn[(size_t)(t0+i)*128 + d];
      float pre = cw3*xv + cw2*p1 + cw1*p2 + cw0*p3 + cb;
      xc_s[i][d] = pre / (1.f + __expf(-pre));  // silu
      p3 = p2; p2 = p1; p1 = xv;
    }
    __syncthreads();
    // dbc = xc @ xproj_w  (16 t x 36 j, each 128 MACs)
    for (int idx = threadIdx.x; idx < 16*36; idx += 128) {
      int t = idx / 36, j = idx % 36;
      float acc = 0.f;
      for (int c = 0; c < 128; c++) acc += xc_s[t][c] * xproj_w[c*36 + j];
      dbc_s[t][j] = acc;
    }
    __syncthreads();
    // dt (registers) + 16 scan steps; write gated y in place into xc_s
    for (int i = 0; i < 16; i++) {
      float pre = dtb + dbc_s[i][0]*dtw0 + dbc_s[i][1]*dtw1 + dbc_s[i][2]*dtw2 + dbc_s[i][3]*dtw3;
      float dtv = (pre > 20.f) ? pre : log1pf(__expf(pre));  // softplus
      float xcv = xc_s[i][d];
      float du = dtv * xcv;
      float y = 0.f;
      #pragma unroll
      for (int s = 0; s < 16; s++) {
        float e = __expf(dtv * a[s]);
        h[s] = e*h[s] + du * dbc_s[i][4+s];
        y += h[s] * dbc_s[i][20+s];
      }
      float yv = y + Dd * xcv;
      float zv = zreg[i];
      xc_s[i][d] = yv * (zv / (1.f + __expf(-zv)));
    }
    __syncthreads();
    // out proj: 16 t x 64 o, each 128 MACs
    for (int i = oth; i < 16; i += 2) {
      float acc = 0.f;
      for (int c = 0; c < 128; c++) acc += xc_s[i][c] * out_w[c*64 + ob];
      On[(size_t)(t0+i)*64 + ob] = acc + outb;
    }
    __syncthreads();
  }
}

// ------------------- K4: window-reverse + skip1 + LN2 -------------------
__global__ __launch_bounds__(256) void k_ln2(
    const float* __restrict__ xT, const float* __restrict__ outw,
    const float* __restrict__ skip1, const float* __restrict__ g2, const float* __restrict__ b2,
    float* __restrict__ x1, float* __restrict__ x2){
  int T = blockIdx.x*4 + (threadIdx.x >> 6);
  int lane = threadIdx.x & 63;
  int b = T / HWp, hw = T % HWp;
  int hh = hw / Ww, ww2 = hw % Ww;
  int n = (b*NWX + (hh>>3))*NWX + (ww2>>3);
  int l = (hh&7)*8 + (ww2&7);
  float xb = outw[((size_t)n*64 + l)*64 + lane];
  float sc = xT[(size_t)T*64 + lane];
  float v = sc * skip1[lane] + xb;
  x1[(size_t)T*64 + lane] = v;
  float s1 = v, s2 = v*v;
  #pragma unroll
  for (int m = 1; m < 64; m <<= 1) { s1 += __shfl_xor(s1, m); s2 += __shfl_xor(s2, m); }
  float mu = s1*(1.f/64.f);
  float var = s2*(1.f/64.f) - mu*mu;
  float rstd = rsqrtf(var + 1e-5f);
  x2[(size_t)T*64 + lane] = (v-mu)*rstd*g2[lane] + b2[lane];
}

// ------------------- K5: CAB conv1 3x3 64->16 + gelu -------------------
__global__ __launch_bounds__(256) void k_conv1(
    const float* __restrict__ x2, const float* __restrict__ w1, const float* __restrict__ bc1,
    float* __restrict__ c1){
  __shared__ float xt[100*65];  // 10x10 pixels, 64 ch (pad 65)
  int b = blockIdx.x / WPB;
  int r = blockIdx.x % WPB;
  int by = r / NWX, bx = r % NWX;
  int lane = threadIdx.x & 63, grp = threadIdx.x >> 6;
  for (int p = grp; p < 100; p += 4) {
    int gy = by*8 + p/10 - 1;
    int gx = bx*8 + p%10 - 1;
    float val = 0.f;
    if (gy >= 0 && gy < Hh && gx >= 0 && gx < Ww)
      val = x2[((size_t)b*HWp + (size_t)gy*Ww + gx)*64 + lane];
    xt[p*65 + lane] = val;
  }
  __syncthreads();
  int co = threadIdx.x & 15;
  int pp = threadIdx.x >> 4;   // 0..15
  int px = pp & 7, py0 = pp >> 3;
  float acc[4] = {0.f,0.f,0.f,0.f};
  for (int ky = 0; ky < 3; ky++)
    for (int kx = 0; kx < 3; kx++)
      for (int ci = 0; ci < 64; ci++) {
        float wv = w1[((co*64+ci)*3+ky)*3+kx];
        #pragma unroll
        for (int j = 0; j < 4; j++)
          acc[j] += xt[((py0+2*j+ky)*10 + px+kx)*65 + ci] * wv;
      }
  float bias = bc1[co];
  #pragma unroll
  for (int j = 0; j < 4; j++) {
    int py = py0 + 2*j;
    float v = acc[j] + bias;
    float gv = 0.5f * v * (1.f + erff(v * 0.70710678118f));
    c1[((size_t)b*HWp + (size_t)(by*8+py)*Ww + bx*8+px)*16 + co] = gv;
  }
}

// ------------------- K6: CAB conv2 3x3 16->64 + partial mean -------------------
__global__ __launch_bounds__(256) void k_conv2(
    const float* __restrict__ c1, const float* __restrict__ w2, const float* __restrict__ bc2,
    float* __restrict__ c2, float* __restrict__ sums){
  __shared__ float xt[100*17];  // 10x10 pixels, 16 ch (pad 17)
  __shared__ float red[4][64];
  int b = blockIdx.x / WPB;
  int r = blockIdx.x % WPB;
  int by = r / NWX, bx = r % NWX;
  for (int idx = threadIdx.x; idx < 1600; idx += 256) {
    int p = idx >> 4, ci = idx & 15;
    int gy = by*8 + p/10 - 1;
    int gx = bx*8 + p%10 - 1;
    float val = 0.f;
    if (gy >= 0 && gy < Hh && gx >= 0 && gx < Ww)
      val = c1[((size_t)b*HWp + (size_t)gy*Ww + gx)*16 + ci];
    xt[p*17 + ci] = val;
  }
  __syncthreads();
  int co = threadIdx.x & 63;
  int pg = threadIdx.x >> 6;   // 0..3 -> pixels pg*16 .. pg*16+15
  float acc[16];
  #pragma unroll
  for (int j = 0; j < 16; j++) acc[j] = 0.f;
  for (int ky = 0; ky < 3; ky++)
    for (int kx = 0; kx < 3; kx++)
      for (int ci = 0; ci < 16; ci++) {
        float wv = w2[((co*16+ci)*3+ky)*3+kx];
        #pragma unroll
        for (int j = 0; j < 16; j++) {
          int pp = pg*16 + j;
          int py = pp >> 3, px = pp & 7;
          acc[j] += xt[((py+ky)*10 + px+kx)*17 + ci] * wv;
        }
      }
  float bias = bc2[co];
  float lsum = 0.f;
  #pragma unroll
  for (int j = 0; j < 16; j++) {
    int pp = pg*16 + j;
    int py = pp >> 3, px = pp & 7;
    float v = acc[j] + bias;
    c2[((size_t)b*HWp + (size_t)(by*8+py)*Ww + bx*8+px)*64 + co] = v;
    lsum += v;
  }
  red[pg][co] = lsum;
  __syncthreads();
  if (threadIdx.x < 64) {
    float s = red[0][threadIdx.x] + red[1][threadIdx.x] + red[2][threadIdx.x] + red[3][threadIdx.x];
    atomicAdd(&sums[b*64 + threadIdx.x], s);
  }
}

// ------------------- K7: channel attention -------------------
__global__ void k_att(const float* __restrict__ sums,
                      const float* __restrict__ wd, const float* __restrict__ bd,
                      const float* __restrict__ wu, const float* __restrict__ bu,
                      float* __restrict__ att){
  int tid = threadIdx.x;            // 128 threads
  int b = tid >> 6, co = tid & 63;
  float inv = 1.f / (float)HWp;
  float hid[4];
  #pragma unroll
  for (int j = 0; j < 4; j++) {
    float acc = bd[j];
    for (int c = 0; c < 64; c++) acc += wd[j*64+c] * (sums[b*64+c] * inv);
    hid[j] = fmaxf(acc, 0.f);
  }
  float acc = bu[co];
  #pragma unroll
  for (int j = 0; j < 4; j++) acc += wu[co*4+j] * hid[j];
  att[tid] = 1.f / (1.f + __expf(-acc));
}

// ------------------- K8: final combine + NHWC -> NCHW -------------------
__global__ __launch_bounds__(256) void k_final(
    const float* __restrict__ x1, const float* __restrict__ c2,
    const float* __restrict__ skip2, const float* __restrict__ att,
    float* __restrict__ out){
  __shared__ float t[64][65];
  int b = blockIdx.x / WPB;
  int hw0 = (blockIdx.x % WPB) * 64;
  int lane = threadIdx.x & 63, grp = threadIdx.x >> 6;
  float sk = skip2[lane], at = att[b*64 + lane];
  #pragma unroll
  for (int r = 0; r < 64; r += 4) {
    int hwl = r + grp;
    size_t T = (size_t)b*HWp + hw0 + hwl;
    t[hwl][lane] = x1[T*64+lane]*sk + c2[T*64+lane]*at;
  }
  __syncthreads();
  float* ob = out + (size_t)b * Cch * HWp;
  #pragma unroll
  for (int r = 0; r < 64; r += 4) {
    int c = r + grp;
    ob[(size_t)c*HWp + hw0 + lane] = t[lane][c];
  }
}

extern "C" void kernel_launch(void* const* d_in, const int* in_sizes, int n_in,
                              void* d_out, int out_size, void* d_ws, size_t ws_size,
                              hipStream_t stream) {
  (void)in_sizes; (void)n_in; (void)out_size; (void)ws_size;
  const float* x      = (const float*)d_in[0];
  const float* ln1_g  = (const float*)d_in[1];
  const float* ln1_b  = (const float*)d_in[2];
  const float* in_w   = (const float*)d_in[3];
  const float* in_b   = (const float*)d_in[4];
  const float* conv_w = (const float*)d_in[5];
  const float* conv_b = (const float*)d_in[6];
  const float* xproj_w= (const float*)d_in[7];
  const float* dt_w   = (const float*)d_in[8];
  const float* dt_b   = (const float*)d_in[9];
  const float* A_log  = (const float*)d_in[10];
  const float* Dp     = (const float*)d_in[11];
  const float* out_w  = (const float*)d_in[12];
  const float* out_b  = (const float*)d_in[13];
  const float* skip1  = (const float*)d_in[14];
  const float* ln2_g  = (const float*)d_in[15];
  const float* ln2_b  = (const float*)d_in[16];
  const float* skip2  = (const float*)d_in[17];
  const float* cab_w1 = (const float*)d_in[18];
  const float* cab_b1 = (const float*)d_in[19];
  const float* cab_w2 = (const float*)d_in[20];
  const float* cab_b2 = (const float*)d_in[21];
  const float* ca_wd  = (const float*)d_in[22];
  const float* ca_bd  = (const float*)d_in[23];
  const float* ca_wu  = (const float*)d_in[24];
  const float* ca_bu  = (const float*)d_in[25];

  float* ws   = (float*)d_ws;
  float* xT   = ws;                       // 4,718,592
  float* Xin  = ws + 4718592;             // 9,437,184  (reused: x2 then x1)
  float* Zbuf = ws + 14155776;            // 9,437,184  (reused: c1, c2)
  float* outw = ws + 23592960;            // 4,718,592
  float* sums = ws + 28311552;            // 128
  float* att  = ws + 28311680;            // 128
  float* x2   = Xin;                      // alias (Xin dead after k_scan)
  float* x1   = Xin + 4718592;            // alias
  float* c1   = Zbuf;                     // alias (Z dead after k_scan)
  float* c2   = Zbuf + 1179648;           // alias

  hipMemsetAsync(sums, 0, 128*sizeof(float), stream);
  k_transpose<<<NW, 256, 0, stream>>>(x, xT);
  k_stage1<<<NW, 256, 0, stream>>>(xT, ln1_g, ln1_b, in_w, in_b, Xin, Zbuf);
  k_scan<<<NW, 128, 0, stream>>>(Xin, Zbuf, conv_w, conv_b, xproj_w, dt_w, dt_b,
                                 A_log, Dp, out_w, out_b, outw);
  k_ln2<<<HWp*Bb/4, 256, 0, stream>>>(xT, outw, skip1, ln2_g, ln2_b, x1, x2);
  k_conv1<<<NW, 256, 0, stream>>>(x2, cab_w1, cab_b1, c1);
  k_conv2<<<NW, 256, 0, stream>>>(c1, cab_w2, cab_b2, c2, sums);
  k_att<<<1, 128, 0, stream>>>(sums, ca_wd, ca_bd, ca_wu, ca_bu, att);
  k_final<<<NW, 256, 0, stream>>>(x1, c2, skip2, att, (float*)d_out);
}

// Round 2
// 486.421 us; speedup vs baseline: 1.5701x; 1.5701x over previous
//
#include <hip/hip_runtime.h>
#include <hip/hip_bf16.h>
#include <math.h>

// Problem constants
#define Hh 192
#define Ww 192
#define HWp (Hh*Ww)          // 36864
#define Bb 2
#define Cch 64
#define DI 128
#define NWX 24               // windows per row
#define WPB 576              // windows per batch
#define NW  1152             // total windows
#define DS 16
#define SHIFT 4

// ------------------- K1: NCHW -> NHWC transpose -------------------
__global__ __launch_bounds__(256) void k_transpose(const float* __restrict__ x, float* __restrict__ xT){
  __shared__ float t[64][65];
  int b   = blockIdx.x / WPB;
  int hw0 = (blockIdx.x % WPB) * 64;
  int lane = threadIdx.x & 63, grp = threadIdx.x >> 6;
  const float* xb = x + (size_t)b * Cch * HWp;
  #pragma unroll
  for (int r = 0; r < 64; r += 4) {
    int c = r + grp;
    t[c][lane] = xb[(size_t)c * HWp + hw0 + lane];
  }
  __syncthreads();
  float* xo = xT + ((size_t)b * HWp + hw0) * 64;
  #pragma unroll
  for (int r = 0; r < 64; r += 4) {
    int hwl = r + grp;
    xo[(size_t)hwl * 64 + lane] = t[lane][hwl];
  }
}

// ------------------- K2: shift + LN1 + in_proj + mask -------------------
__global__ __launch_bounds__(256) void k_stage1(
    const float* __restrict__ xT, const float* __restrict__ g1, const float* __restrict__ b1,
    const float* __restrict__ in_w, const float* __restrict__ in_b,
    float* __restrict__ Xin, float* __restrict__ Zb){
  __shared__ __align__(16) float xs[64][68];
  int n = blockIdx.x;
  int b = n / WPB, wi = n % WPB;
  int wy = wi / NWX, wx = wi % NWX;
  int tid = threadIdx.x;
  int l = tid >> 2, q = tid & 3;       // token l (0..63), quarter q
  int iy = l >> 3, ix = l & 7;
  int h = wy*8 + iy, w = wx*8 + ix;    // shifted-space coords
  int hs = h + SHIFT; if (hs >= Hh) hs -= Hh;
  int ws2 = w + SHIFT; if (ws2 >= Ww) ws2 -= Ww;
  const float* src = xT + ((size_t)b*HWp + (size_t)hs*Ww + ws2) * 64 + q*16;
  float v[16];
  float s1 = 0.f, s2 = 0.f;
  #pragma unroll
  for (int k = 0; k < 4; k++) {
    float4 f = *reinterpret_cast<const float4*>(src + k*4);
    v[k*4+0]=f.x; v[k*4+1]=f.y; v[k*4+2]=f.z; v[k*4+3]=f.w;
  }
  #pragma unroll
  for (int i = 0; i < 16; i++) { s1 += v[i]; s2 += v[i]*v[i]; }
  s1 += __shfl_xor(s1, 1); s2 += __shfl_xor(s2, 1);
  s1 += __shfl_xor(s1, 2); s2 += __shfl_xor(s2, 2);
  float mu = s1 * (1.f/64.f);
  float var = s2 * (1.f/64.f) - mu*mu;
  float rstd = rsqrtf(var + 1e-5f);
  #pragma unroll
  for (int i = 0; i < 16; i++) {
    int c = q*16 + i;
    xs[l][c] = (v[i]-mu)*rstd*g1[c] + b1[c];
  }
  __syncthreads();
  // GEMM: 64 tokens x (64 -> 256). thread owns output column o = tid.
  int o = tid;
  float bias = in_b[o];
  for (int lc = 0; lc < 64; lc += 8) {
    float acc[8] = {0.f,0.f,0.f,0.f,0.f,0.f,0.f,0.f};
    for (int c = 0; c < 64; c++) {
      float wv = in_w[c*256 + o];
      #pragma unroll
      for (int j = 0; j < 8; j++) acc[j] += xs[lc+j][c] * wv;
    }
    #pragma unroll
    for (int j = 0; j < 8; j++) {
      int l2 = lc + j;
      float val = acc[j] + bias;
      int hh = wy*8 + (l2>>3), ww2 = wx*8 + (l2&7);
      if (o < 128) {
        float m = (hh < Hh-SHIFT && ww2 < Ww-SHIFT) ? 1.f : 0.f;
        Xin[((size_t)n*64 + l2)*128 + o] = val * m;
      } else {
        Zb[((size_t)n*64 + l2)*128 + (o-128)] = val;
      }
    }
  }
}

// ------------------- K3: conv1d + xproj + dt + scan + gate + out_proj -------------------
__global__ __launch_bounds__(128) void k_scan(
    const float* __restrict__ Xin, const float* __restrict__ Zb,
    const float* __restrict__ conv_w, const float* __restrict__ conv_b,
    const float* __restrict__ xproj_w,
    const float* __restrict__ dt_w, const float* __restrict__ dt_b,
    const float* __restrict__ A_log, const float* __restrict__ Dp,
    const float* __restrict__ out_w, const float* __restrict__ out_b,
    float* __restrict__ outw){
  __shared__ float xc_s[16][129];
  __shared__ float dbc_s[16][40];
  int n = blockIdx.x;
  int d = threadIdx.x; // 0..127
  float cw0 = conv_w[d], cw1 = conv_w[128+d], cw2 = conv_w[256+d], cw3 = conv_w[384+d];
  float cb  = conv_b[d];
  float a[16];
  #pragma unroll
  for (int s = 0; s < 16; s++) a[s] = -expf(A_log[d*16+s]);
  float dtb  = dt_b[d];
  float dtw0 = dt_w[d], dtw1 = dt_w[128+d], dtw2 = dt_w[256+d], dtw3 = dt_w[384+d];
  float Dd = Dp[d];
  float h[16];
  #pragma unroll
  for (int s = 0; s < 16; s++) h[s] = 0.f;
  float p1 = 0.f, p2 = 0.f, p3 = 0.f;  // conv history x[t-1], x[t-2], x[t-3]
  const float* Xn = Xin + (size_t)n*64*128;
  const float* Zn = Zb  + (size_t)n*64*128;
  float* On = outw + (size_t)n*64*64;
  int ob  = threadIdx.x & 63;
  int oth = threadIdx.x >> 6;
  float outb = out_b[ob];

  for (int ch = 0; ch < 4; ch++) {
    int t0 = ch*16;
    float zreg[16];
    // load + causal conv(K=4) + silu -> xc_s
    #pragma unroll
    for (int i = 0; i < 16; i++) {
      float xv = Xn[(size_t)(t0+i)*128 + d];
      zreg[i]  = Zn[(size_t)(t0+i)*128 + d];
      float pre = cw3*xv + cw2*p1 + cw1*p2 + cw0*p3 + cb;
      xc_s[i][d] = pre / (1.f + __expf(-pre));  // silu
      p3 = p2; p2 = p1; p1 = xv;
    }
    __syncthreads();
    // dbc = xc @ xproj_w  (16 t x 36 j, each 128 MACs)
    for (int idx = threadIdx.x; idx < 16*36; idx += 128) {
      int t = idx / 36, j = idx % 36;
      float acc = 0.f;
      for (int c = 0; c < 128; c++) acc += xc_s[t][c] * xproj_w[c*36 + j];
      dbc_s[t][j] = acc;
    }
    __syncthreads();
    // dt (registers) + 16 scan steps; write gated y in place into xc_s
    for (int i = 0; i < 16; i++) {
      float pre = dtb + dbc_s[i][0]*dtw0 + dbc_s[i][1]*dtw1 + dbc_s[i][2]*dtw2 + dbc_s[i][3]*dtw3;
      float dtv = (pre > 20.f) ? pre : log1pf(__expf(pre));  // softplus
      float xcv = xc_s[i][d];
      float du = dtv * xcv;
      float y = 0.f;
      #pragma unroll
      for (int s = 0; s < 16; s++) {
        float e = __expf(dtv * a[s]);
        h[s] = e*h[s] + du * dbc_s[i][4+s];
        y += h[s] * dbc_s[i][20+s];
      }
      float yv = y + Dd * xcv;
      float zv = zreg[i];
      xc_s[i][d] = yv * (zv / (1.f + __expf(-zv)));
    }
    __syncthreads();
    // out proj: 16 t x 64 o, each 128 MACs
    for (int i = oth; i < 16; i += 2) {
      float acc = 0.f;
      for (int c = 0; c < 128; c++) acc += xc_s[i][c] * out_w[c*64 + ob];
      On[(size_t)(t0+i)*64 + ob] = acc + outb;
    }
    __syncthreads();
  }
}

// ------------------- K4: window-reverse + skip1 + LN2 -------------------
__global__ __launch_bounds__(256) void k_ln2(
    const float* __restrict__ xT, const float* __restrict__ outw,
    const float* __restrict__ skip1, const float* __restrict__ g2, const float* __restrict__ b2,
    float* __restrict__ x1, float* __restrict__ x2){
  int T = blockIdx.x*4 + (threadIdx.x >> 6);
  int lane = threadIdx.x & 63;
  int b = T / HWp, hw = T % HWp;
  int hh = hw / Ww, ww2 = hw % Ww;
  int n = (b*NWX + (hh>>3))*NWX + (ww2>>3);
  int l = (hh&7)*8 + (ww2&7);
  float xb = outw[((size_t)n*64 + l)*64 + lane];
  float sc = xT[(size_t)T*64 + lane];
  float v = sc * skip1[lane] + xb;
  x1[(size_t)T*64 + lane] = v;
  float s1 = v, s2 = v*v;
  #pragma unroll
  for (int m = 1; m < 64; m <<= 1) { s1 += __shfl_xor(s1, m); s2 += __shfl_xor(s2, m); }
  float mu = s1*(1.f/64.f);
  float var = s2*(1.f/64.f) - mu*mu;
  float rstd = rsqrtf(var + 1e-5f);
  x2[(size_t)T*64 + lane] = (v-mu)*rstd*g2[lane] + b2[lane];
}

// ------------------- K5: CAB conv1 3x3 64->16 + gelu (LDS-staged weights) -------------------
__global__ __launch_bounds__(256) void k_conv1(
    const float* __restrict__ x2, const float* __restrict__ w1, const float* __restrict__ bc1,
    float* __restrict__ c1){
  __shared__ float xt[100][68];      // 10x10 pixels x 64 ch (pad 68) = 27.2 KB
  __shared__ float w_s[9][64][16];   // [tap][ci][co] = 36.9 KB
  int b = blockIdx.x / WPB;
  int r = blockIdx.x % WPB;
  int by = r / NWX, bx = r % NWX;
  // stage weights: w1 layout [co][ci][ky][kx]
  for (int idx = threadIdx.x; idx < 9216; idx += 256) {
    int co = idx & 15, ci = (idx >> 4) & 63, tap = idx >> 10;
    w_s[tap][ci][co] = w1[(co*64 + ci)*9 + tap];
  }
  int lane = threadIdx.x & 63, grp = threadIdx.x >> 6;
  for (int p = grp; p < 100; p += 4) {
    int gy = by*8 + p/10 - 1;
    int gx = bx*8 + p%10 - 1;
    float val = 0.f;
    if (gy >= 0 && gy < Hh && gx >= 0 && gx < Ww)
      val = x2[((size_t)b*HWp + (size_t)gy*Ww + gx)*64 + lane];
    xt[p][lane] = val;
  }
  __syncthreads();
  int co = threadIdx.x & 15;
  int pp = threadIdx.x >> 4;   // 0..15
  int px = pp & 7, py0 = pp >> 3;
  float acc[4] = {0.f,0.f,0.f,0.f};
  #pragma unroll
  for (int tap = 0; tap < 9; tap++) {
    int ky = tap / 3, kx = tap % 3;
    const float* x0 = &xt[(py0+0+ky)*10 + px+kx][0];
    const float* x1p = &xt[(py0+2+ky)*10 + px+kx][0];
    const float* x2p = &xt[(py0+4+ky)*10 + px+kx][0];
    const float* x3p = &xt[(py0+6+ky)*10 + px+kx][0];
    #pragma unroll 4
    for (int ci = 0; ci < 64; ci++) {
      float wv = w_s[tap][ci][co];
      acc[0] += x0[ci]  * wv;
      acc[1] += x1p[ci] * wv;
      acc[2] += x2p[ci] * wv;
      acc[3] += x3p[ci] * wv;
    }
  }
  float bias = bc1[co];
  #pragma unroll
  for (int j = 0; j < 4; j++) {
    int py = py0 + 2*j;
    float v = acc[j] + bias;
    float gv = 0.5f * v * (1.f + erff(v * 0.70710678118f));
    c1[((size_t)b*HWp + (size_t)(by*8+py)*Ww + bx*8+px)*16 + co] = gv;
  }
}

// ------------------- K6: CAB conv2 3x3 16->64 + partial mean (LDS-staged weights) -------------------
__global__ __launch_bounds__(256) void k_conv2(
    const float* __restrict__ c1, const float* __restrict__ w2, const float* __restrict__ bc2,
    float* __restrict__ c2, float* __restrict__ sums){
  __shared__ float xt[100][17];      // 6.8 KB
  __shared__ float w_s[9][16][64];   // [tap][ci][co] = 36.9 KB
  __shared__ float red[4][64];
  int b = blockIdx.x / WPB;
  int r = blockIdx.x % WPB;
  int by = r / NWX, bx = r % NWX;
  // stage weights: w2 layout [co][ci][ky][kx]
  for (int idx = threadIdx.x; idx < 9216; idx += 256) {
    int co = idx & 63, ci = (idx >> 6) & 15, tap = idx >> 10;
    w_s[tap][ci][co] = w2[(co*16 + ci)*9 + tap];
  }
  for (int idx = threadIdx.x; idx < 1600; idx += 256) {
    int p = idx >> 4, ci = idx & 15;
    int gy = by*8 + p/10 - 1;
    int gx = bx*8 + p%10 - 1;
    float val = 0.f;
    if (gy >= 0 && gy < Hh && gx >= 0 && gx < Ww)
      val = c1[((size_t)b*HWp + (size_t)gy*Ww + gx)*16 + ci];
    xt[p][ci] = val;
  }
  __syncthreads();
  int co = threadIdx.x & 63;
  int pg = threadIdx.x >> 6;   // 0..3 -> pixels pg*16 .. pg*16+15
  float acc[16];
  #pragma unroll
  for (int j = 0; j < 16; j++) acc[j] = 0.f;
  #pragma unroll
  for (int tap = 0; tap < 9; tap++) {
    int ky = tap / 3, kx = tap % 3;
    #pragma unroll
    for (int ci = 0; ci < 16; ci++) {
      float wv = w_s[tap][ci][co];
      #pragma unroll
      for (int j = 0; j < 16; j++) {
        int pp = pg*16 + j;
        int py = pp >> 3, px = pp & 7;
        acc[j] += xt[(py+ky)*10 + px+kx][ci] * wv;
      }
    }
  }
  float bias = bc2[co];
  float lsum = 0.f;
  #pragma unroll
  for (int j = 0; j < 16; j++) {
    int pp = pg*16 + j;
    int py = pp >> 3, px = pp & 7;
    float v = acc[j] + bias;
    c2[((size_t)b*HWp + (size_t)(by*8+py)*Ww + bx*8+px)*64 + co] = v;
    lsum += v;
  }
  red[pg][co] = lsum;
  __syncthreads();
  if (threadIdx.x < 64) {
    float s = red[0][threadIdx.x] + red[1][threadIdx.x] + red[2][threadIdx.x] + red[3][threadIdx.x];
    atomicAdd(&sums[b*64 + threadIdx.x], s);
  }
}

// ------------------- K7: channel attention -------------------
__global__ void k_att(const float* __restrict__ sums,
                      const float* __restrict__ wd, const float* __restrict__ bd,
                      const float* __restrict__ wu, const float* __restrict__ bu,
                      float* __restrict__ att){
  int tid = threadIdx.x;            // 128 threads
  int b = tid >> 6, co = tid & 63;
  float inv = 1.f / (float)HWp;
  float hid[4];
  #pragma unroll
  for (int j = 0; j < 4; j++) {
    float acc = bd[j];
    for (int c = 0; c < 64; c++) acc += wd[j*64+c] * (sums[b*64+c] * inv);
    hid[j] = fmaxf(acc, 0.f);
  }
  float acc = bu[co];
  #pragma unroll
  for (int j = 0; j < 4; j++) acc += wu[co*4+j] * hid[j];
  att[tid] = 1.f / (1.f + __expf(-acc));
}

// ------------------- K8: final combine + NHWC -> NCHW -------------------
__global__ __launch_bounds__(256) void k_final(
    const float* __restrict__ x1, const float* __restrict__ c2,
    const float* __restrict__ skip2, const float* __restrict__ att,
    float* __restrict__ out){
  __shared__ float t[64][65];
  int b = blockIdx.x / WPB;
  int hw0 = (blockIdx.x % WPB) * 64;
  int lane = threadIdx.x & 63, grp = threadIdx.x >> 6;
  float sk = skip2[lane], at = att[b*64 + lane];
  #pragma unroll
  for (int r = 0; r < 64; r += 4) {
    int hwl = r + grp;
    size_t T = (size_t)b*HWp + hw0 + hwl;
    t[hwl][lane] = x1[T*64+lane]*sk + c2[T*64+lane]*at;
  }
  __syncthreads();
  float* ob = out + (size_t)b * Cch * HWp;
  #pragma unroll
  for (int r = 0; r < 64; r += 4) {
    int c = r + grp;
    ob[(size_t)c*HWp + hw0 + lane] = t[lane][c];
  }
}

extern "C" void kernel_launch(void* const* d_in, const int* in_sizes, int n_in,
                              void* d_out, int out_size, void* d_ws, size_t ws_size,
                              hipStream_t stream) {
  (void)in_sizes; (void)n_in; (void)out_size; (void)ws_size;
  const float* x      = (const float*)d_in[0];
  const float* ln1_g  = (const float*)d_in[1];
  const float* ln1_b  = (const float*)d_in[2];
  const float* in_w   = (const float*)d_in[3];
  const float* in_b   = (const float*)d_in[4];
  const float* conv_w = (const float*)d_in[5];
  const float* conv_b = (const float*)d_in[6];
  const float* xproj_w= (const float*)d_in[7];
  const float* dt_w   = (const float*)d_in[8];
  const float* dt_b   = (const float*)d_in[9];
  const float* A_log  = (const float*)d_in[10];
  const float* Dp     = (const float*)d_in[11];
  const float* out_w  = (const float*)d_in[12];
  const float* out_b  = (const float*)d_in[13];
  const float* skip1  = (const float*)d_in[14];
  const float* ln2_g  = (const float*)d_in[15];
  const float* ln2_b  = (const float*)d_in[16];
  const float* skip2  = (const float*)d_in[17];
  const float* cab_w1 = (const float*)d_in[18];
  const float* cab_b1 = (const float*)d_in[19];
  const float* cab_w2 = (const float*)d_in[20];
  const float* cab_b2 = (const float*)d_in[21];
  const float* ca_wd  = (const float*)d_in[22];
  const float* ca_bd  = (const float*)d_in[23];
  const float* ca_wu  = (const float*)d_in[24];
  const float* ca_bu  = (const float*)d_in[25];

  float* ws   = (float*)d_ws;
  float* xT   = ws;                       // 4,718,592
  float* Xin  = ws + 4718592;             // 9,437,184  (reused: x2 then x1)
  float* Zbuf = ws + 14155776;            // 9,437,184  (reused: c1, c2)
  float* outw = ws + 23592960;            // 4,718,592
  float* sums = ws + 28311552;            // 128
  float* att  = ws + 28311680;            // 128
  float* x2   = Xin;                      // alias (Xin dead after k_scan)
  float* x1   = Xin + 4718592;            // alias
  float* c1   = Zbuf;                     // alias (Z dead after k_scan)
  float* c2   = Zbuf + 1179648;           // alias

  hipMemsetAsync(sums, 0, 128*sizeof(float), stream);
  k_transpose<<<NW, 256, 0, stream>>>(x, xT);
  k_stage1<<<NW, 256, 0, stream>>>(xT, ln1_g, ln1_b, in_w, in_b, Xin, Zbuf);
  k_scan<<<NW, 128, 0, stream>>>(Xin, Zbuf, conv_w, conv_b, xproj_w, dt_w, dt_b,
                                 A_log, Dp, out_w, out_b, outw);
  k_ln2<<<HWp*Bb/4, 256, 0, stream>>>(xT, outw, skip1, ln2_g, ln2_b, x1, x2);
  k_conv1<<<NW, 256, 0, stream>>>(x2, cab_w1, cab_b1, c1);
  k_conv2<<<NW, 256, 0, stream>>>(c1, cab_w2, cab_b2, c2, sums);
  k_att<<<1, 128, 0, stream>>>(sums, ca_wd, ca_bd, ca_wu, ca_bu, att);
  k_final<<<NW, 256, 0, stream>>>(x1, c2, skip2, att, (float*)d_out);
}

// Round 3
// 447.447 us; speedup vs baseline: 1.7069x; 1.0871x over previous
//
#include <hip/hip_runtime.h>
#include <hip/hip_bf16.h>
#include <math.h>

// Problem constants
#define Hh 192
#define Ww 192
#define HWp (Hh*Ww)          // 36864
#define Bb 2
#define Cch 64
#define DI 128
#define NWX 24               // windows per row
#define WPB 576              // windows per batch
#define NW  1152             // total windows
#define DS 16
#define SHIFT 4

// ------------------- K1: NCHW -> NHWC transpose -------------------
__global__ __launch_bounds__(256) void k_transpose(const float* __restrict__ x, float* __restrict__ xT){
  __shared__ float t[64][65];
  int b   = blockIdx.x / WPB;
  int hw0 = (blockIdx.x % WPB) * 64;
  int lane = threadIdx.x & 63, grp = threadIdx.x >> 6;
  const float* xb = x + (size_t)b * Cch * HWp;
  #pragma unroll
  for (int r = 0; r < 64; r += 4) {
    int c = r + grp;
    t[c][lane] = xb[(size_t)c * HWp + hw0 + lane];
  }
  __syncthreads();
  float* xo = xT + ((size_t)b * HWp + hw0) * 64;
  #pragma unroll
  for (int r = 0; r < 64; r += 4) {
    int hwl = r + grp;
    xo[(size_t)hwl * 64 + lane] = t[lane][hwl];
  }
}

// ------------------- K2: shift + LN1 + in_proj + mask + conv1d + silu -------------------
__global__ __launch_bounds__(256) void k_stage1(
    const float* __restrict__ xT, const float* __restrict__ g1, const float* __restrict__ b1,
    const float* __restrict__ in_w, const float* __restrict__ in_b,
    const float* __restrict__ conv_w, const float* __restrict__ conv_b,
    float* __restrict__ xc, float* __restrict__ Zb){
  __shared__ __align__(16) float xs[64][68];
  int n = blockIdx.x;
  int b = n / WPB, wi = n % WPB;
  int wy = wi / NWX, wx = wi % NWX;
  int tid = threadIdx.x;
  int l = tid >> 2, q = tid & 3;       // token l (0..63), quarter q
  int iy = l >> 3, ix = l & 7;
  int h = wy*8 + iy, w = wx*8 + ix;    // shifted-space coords
  int hs = h + SHIFT; if (hs >= Hh) hs -= Hh;
  int ws2 = w + SHIFT; if (ws2 >= Ww) ws2 -= Ww;
  const float* src = xT + ((size_t)b*HWp + (size_t)hs*Ww + ws2) * 64 + q*16;
  float v[16];
  float s1 = 0.f, s2 = 0.f;
  #pragma unroll
  for (int k = 0; k < 4; k++) {
    float4 f = *reinterpret_cast<const float4*>(src + k*4);
    v[k*4+0]=f.x; v[k*4+1]=f.y; v[k*4+2]=f.z; v[k*4+3]=f.w;
  }
  #pragma unroll
  for (int i = 0; i < 16; i++) { s1 += v[i]; s2 += v[i]*v[i]; }
  s1 += __shfl_xor(s1, 1); s2 += __shfl_xor(s2, 1);
  s1 += __shfl_xor(s1, 2); s2 += __shfl_xor(s2, 2);
  float mu = s1 * (1.f/64.f);
  float var = s2 * (1.f/64.f) - mu*mu;
  float rstd = rsqrtf(var + 1e-5f);
  #pragma unroll
  for (int i = 0; i < 16; i++) {
    int c = q*16 + i;
    xs[l][c] = (v[i]-mu)*rstd*g1[c] + b1[c];
  }
  __syncthreads();
  // GEMM: 64 tokens x (64 -> 256). thread owns output column o = tid.
  int o = tid;
  float bias = in_b[o];
  // conv weights/state (only used for o<128; index is always valid)
  int dd = o & 127;
  float cw0 = conv_w[dd], cw1 = conv_w[128+dd], cw2 = conv_w[256+dd], cw3 = conv_w[384+dd];
  float cb = conv_b[dd];
  float p1 = 0.f, p2 = 0.f, p3 = 0.f;
  for (int lc = 0; lc < 64; lc += 8) {
    float acc[8] = {0.f,0.f,0.f,0.f,0.f,0.f,0.f,0.f};
    for (int c = 0; c < 64; c++) {
      float wv = in_w[c*256 + o];
      #pragma unroll
      for (int j = 0; j < 8; j++) acc[j] += xs[lc+j][c] * wv;
    }
    if (o < 128) {
      #pragma unroll
      for (int j = 0; j < 8; j++) {
        int l2 = lc + j;
        int hh = wy*8 + (l2>>3), ww2 = wx*8 + (l2&7);
        float m = (hh < Hh-SHIFT && ww2 < Ww-SHIFT) ? 1.f : 0.f;
        float xv = (acc[j] + bias) * m;      // masked x_in
        float pre = cw3*xv + cw2*p1 + cw1*p2 + cw0*p3 + cb;
        xc[((size_t)n*64 + l2)*128 + o] = pre / (1.f + __expf(-pre));  // silu
        p3 = p2; p2 = p1; p1 = xv;
      }
    } else {
      #pragma unroll
      for (int j = 0; j < 8; j++)
        Zb[((size_t)n*64 + lc + j)*128 + (o-128)] = acc[j] + bias;
    }
  }
}

// ------------------- K3: dbc = xc @ xproj_w  (per-window 64x128 @ 128x36) -------------------
__global__ __launch_bounds__(256) void k_dbc(
    const float* __restrict__ xc, const float* __restrict__ xproj_w,
    float* __restrict__ dbc){
  __shared__ __align__(16) float xs[64][132];
  __shared__ float ws[128][37];
  int n = blockIdx.x;
  const float4* src = reinterpret_cast<const float4*>(xc + (size_t)n*8192);
  #pragma unroll
  for (int k = 0; k < 8; k++) {
    int gi = threadIdx.x + k*256;
    int t = gi >> 5, d4 = gi & 31;
    *reinterpret_cast<float4*>(&xs[t][d4*4]) = src[gi];
  }
  for (int idx = threadIdx.x; idx < 4608; idx += 256) {
    int c = idx / 36, j = idx - c*36;
    ws[c][j] = xproj_w[idx];
  }
  __syncthreads();
  int t = threadIdx.x >> 2, jq = threadIdx.x & 3;
  float acc[9];
  #pragma unroll
  for (int u = 0; u < 9; u++) acc[u] = 0.f;
  for (int c = 0; c < 128; c++) {
    float xv = xs[t][c];
    #pragma unroll
    for (int u = 0; u < 9; u++) acc[u] += xv * ws[c][jq*9+u];
  }
  float* dst = dbc + ((size_t)n*64 + t)*36 + jq*9;
  #pragma unroll
  for (int u = 0; u < 9; u++) dst[u] = acc[u];
}

// ------------------- K4: dt + selective scan + gate (g written in-place over xc) -------------------
__global__ __launch_bounds__(128) void k_scan2(
    float* __restrict__ xc,           // in: xc ; out: g = (y + D*xc)*silu(z)
    const float* __restrict__ Zb, const float* __restrict__ dbc,
    const float* __restrict__ dt_w, const float* __restrict__ dt_b,
    const float* __restrict__ A_log, const float* __restrict__ Dp){
  __shared__ float dbc_s[16][40];
  int n = blockIdx.x;
  int d = threadIdx.x; // 0..127
  float a[16];
  #pragma unroll
  for (int s = 0; s < 16; s++) a[s] = -__expf(A_log[d*16+s]);
  float dtb  = dt_b[d];
  float dtw0 = dt_w[d], dtw1 = dt_w[128+d], dtw2 = dt_w[256+d], dtw3 = dt_w[384+d];
  float Dd = Dp[d];
  float h[16];
  #pragma unroll
  for (int s = 0; s < 16; s++) h[s] = 0.f;
  float* Xn = xc + (size_t)n*64*128;
  const float* Zn = Zb  + (size_t)n*64*128;
  const float* Dn = dbc + (size_t)n*64*36;

  for (int ch = 0; ch < 4; ch++) {
    int t0 = ch*16;
    __syncthreads();
    for (int idx = threadIdx.x; idx < 576; idx += 128) {
      int t = idx / 36, j = idx - t*36;
      dbc_s[t][j] = Dn[(t0+t)*36 + j];
    }
    __syncthreads();
    for (int i = 0; i < 16; i++) {
      float xcv = Xn[(size_t)(t0+i)*128 + d];
      float zv  = Zn[(size_t)(t0+i)*128 + d];
      float pre = dtb + dbc_s[i][0]*dtw0 + dbc_s[i][1]*dtw1 + dbc_s[i][2]*dtw2 + dbc_s[i][3]*dtw3;
      float dtv = (pre > 20.f) ? pre : log1pf(__expf(pre));  // softplus
      float du = dtv * xcv;
      float y = 0.f;
      #pragma unroll
      for (int s = 0; s < 16; s++) {
        float e = __expf(dtv * a[s]);
        h[s] = e*h[s] + du * dbc_s[i][4+s];
        y += h[s] * dbc_s[i][20+s];
      }
      float yv = y + Dd * xcv;
      Xn[(size_t)(t0+i)*128 + d] = yv * (zv / (1.f + __expf(-zv)));
    }
  }
}

// ------------------- K5: out_proj + window-reverse + skip1 + LN2 -------------------
__global__ __launch_bounds__(256) void k_out(
    const float* __restrict__ xT, const float* __restrict__ g,
    const float* __restrict__ out_w, const float* __restrict__ out_b,
    const float* __restrict__ skip1, const float* __restrict__ g2, const float* __restrict__ b2,
    float* __restrict__ x1, float* __restrict__ x2){
  __shared__ __align__(16) float gs[64][132];
  __shared__ float outs[64][65];
  int n = blockIdx.x;
  int b = n / WPB, wi = n % WPB;
  int wy = wi / NWX, wx = wi % NWX;
  const float4* src = reinterpret_cast<const float4*>(g + (size_t)n*8192);
  #pragma unroll
  for (int k = 0; k < 8; k++) {
    int gi = threadIdx.x + k*256;
    int t = gi >> 5, d4 = gi & 31;
    *reinterpret_cast<float4*>(&gs[t][d4*4]) = src[gi];
  }
  __syncthreads();
  int o = threadIdx.x & 63, tg = threadIdx.x >> 6;
  float acc[16];
  #pragma unroll
  for (int i = 0; i < 16; i++) acc[i] = 0.f;
  for (int c = 0; c < 128; c++) {
    float wv = out_w[c*64 + o];
    #pragma unroll
    for (int i = 0; i < 16; i++) acc[i] += gs[tg*16 + i][c] * wv;
  }
  float obv = out_b[o];
  #pragma unroll
  for (int i = 0; i < 16; i++) outs[tg*16 + i][o] = acc[i] + obv;
  __syncthreads();
  // LN per token (4 lanes per token, 16 ch each)
  int l = threadIdx.x >> 2, q = threadIdx.x & 3;
  int hh = wy*8 + (l>>3), ww2 = wx*8 + (l&7);
  size_t T = (size_t)b*HWp + (size_t)hh*Ww + ww2;
  float v[16];
  float s1 = 0.f, s2 = 0.f;
  #pragma unroll
  for (int i = 0; i < 16; i++) {
    int c = q*16 + i;
    float val = xT[T*64 + c] * skip1[c] + outs[l][c];
    v[i] = val; s1 += val; s2 += val*val;
  }
  s1 += __shfl_xor(s1, 1); s2 += __shfl_xor(s2, 1);
  s1 += __shfl_xor(s1, 2); s2 += __shfl_xor(s2, 2);
  float mu = s1*(1.f/64.f);
  float var = s2*(1.f/64.f) - mu*mu;
  float rstd = rsqrtf(var + 1e-5f);
  #pragma unroll
  for (int i = 0; i < 16; i++) {
    int c = q*16 + i;
    x1[T*64 + c] = v[i];
    x2[T*64 + c] = (v[i]-mu)*rstd*g2[c] + b2[c];
  }
}

// ------------------- K6: CAB conv1 3x3 64->16 + gelu (LDS-staged weights) -------------------
__global__ __launch_bounds__(256) void k_conv1(
    const float* __restrict__ x2, const float* __restrict__ w1, const float* __restrict__ bc1,
    float* __restrict__ c1){
  __shared__ float xt[100][68];      // 10x10 pixels x 64 ch (pad 68) = 27.2 KB
  __shared__ float w_s[9][64][16];   // [tap][ci][co] = 36.9 KB
  int b = blockIdx.x / WPB;
  int r = blockIdx.x % WPB;
  int by = r / NWX, bx = r % NWX;
  for (int idx = threadIdx.x; idx < 9216; idx += 256) {
    int co = idx & 15, ci = (idx >> 4) & 63, tap = idx >> 10;
    w_s[tap][ci][co] = w1[(co*64 + ci)*9 + tap];
  }
  int lane = threadIdx.x & 63, grp = threadIdx.x >> 6;
  for (int p = grp; p < 100; p += 4) {
    int gy = by*8 + p/10 - 1;
    int gx = bx*8 + p%10 - 1;
    float val = 0.f;
    if (gy >= 0 && gy < Hh && gx >= 0 && gx < Ww)
      val = x2[((size_t)b*HWp + (size_t)gy*Ww + gx)*64 + lane];
    xt[p][lane] = val;
  }
  __syncthreads();
  int co = threadIdx.x & 15;
  int pp = threadIdx.x >> 4;   // 0..15
  int px = pp & 7, py0 = pp >> 3;
  float acc[4] = {0.f,0.f,0.f,0.f};
  #pragma unroll
  for (int tap = 0; tap < 9; tap++) {
    int ky = tap / 3, kx = tap % 3;
    const float* x0  = &xt[(py0+0+ky)*10 + px+kx][0];
    const float* x1p = &xt[(py0+2+ky)*10 + px+kx][0];
    const float* x2p = &xt[(py0+4+ky)*10 + px+kx][0];
    const float* x3p = &xt[(py0+6+ky)*10 + px+kx][0];
    #pragma unroll 4
    for (int ci = 0; ci < 64; ci++) {
      float wv = w_s[tap][ci][co];
      acc[0] += x0[ci]  * wv;
      acc[1] += x1p[ci] * wv;
      acc[2] += x2p[ci] * wv;
      acc[3] += x3p[ci] * wv;
    }
  }
  float bias = bc1[co];
  #pragma unroll
  for (int j = 0; j < 4; j++) {
    int py = py0 + 2*j;
    float v = acc[j] + bias;
    float gv = 0.5f * v * (1.f + erff(v * 0.70710678118f));
    c1[((size_t)b*HWp + (size_t)(by*8+py)*Ww + bx*8+px)*16 + co] = gv;
  }
}

// ------------------- K7: CAB conv2 3x3 16->64 + partial mean (LDS-staged weights) -------------------
__global__ __launch_bounds__(256) void k_conv2(
    const float* __restrict__ c1, const float* __restrict__ w2, const float* __restrict__ bc2,
    float* __restrict__ c2, float* __restrict__ sums){
  __shared__ float xt[100][17];      // 6.8 KB
  __shared__ float w_s[9][16][64];   // [tap][ci][co] = 36.9 KB
  __shared__ float red[4][64];
  int b = blockIdx.x / WPB;
  int r = blockIdx.x % WPB;
  int by = r / NWX, bx = r % NWX;
  for (int idx = threadIdx.x; idx < 9216; idx += 256) {
    int co = idx & 63, ci = (idx >> 6) & 15, tap = idx >> 10;
    w_s[tap][ci][co] = w2[(co*16 + ci)*9 + tap];
  }
  for (int idx = threadIdx.x; idx < 1600; idx += 256) {
    int p = idx >> 4, ci = idx & 15;
    int gy = by*8 + p/10 - 1;
    int gx = bx*8 + p%10 - 1;
    float val = 0.f;
    if (gy >= 0 && gy < Hh && gx >= 0 && gx < Ww)
      val = c1[((size_t)b*HWp + (size_t)gy*Ww + gx)*16 + ci];
    xt[p][ci] = val;
  }
  __syncthreads();
  int co = threadIdx.x & 63;
  int pg = threadIdx.x >> 6;   // 0..3 -> pixels pg*16 .. pg*16+15
  float acc[16];
  #pragma unroll
  for (int j = 0; j < 16; j++) acc[j] = 0.f;
  #pragma unroll
  for (int tap = 0; tap < 9; tap++) {
    int ky = tap / 3, kx = tap % 3;
    #pragma unroll
    for (int ci = 0; ci < 16; ci++) {
      float wv = w_s[tap][ci][co];
      #pragma unroll
      for (int j = 0; j < 16; j++) {
        int pp = pg*16 + j;
        int py = pp >> 3, px = pp & 7;
        acc[j] += xt[(py+ky)*10 + px+kx][ci] * wv;
      }
    }
  }
  float bias = bc2[co];
  float lsum = 0.f;
  #pragma unroll
  for (int j = 0; j < 16; j++) {
    int pp = pg*16 + j;
    int py = pp >> 3, px = pp & 7;
    float v = acc[j] + bias;
    c2[((size_t)b*HWp + (size_t)(by*8+py)*Ww + bx*8+px)*64 + co] = v;
    lsum += v;
  }
  red[pg][co] = lsum;
  __syncthreads();
  if (threadIdx.x < 64) {
    float s = red[0][threadIdx.x] + red[1][threadIdx.x] + red[2][threadIdx.x] + red[3][threadIdx.x];
    atomicAdd(&sums[b*64 + threadIdx.x], s);
  }
}

// ------------------- K8: channel attention -------------------
__global__ void k_att(const float* __restrict__ sums,
                      const float* __restrict__ wd, const float* __restrict__ bd,
                      const float* __restrict__ wu, const float* __restrict__ bu,
                      float* __restrict__ att){
  int tid = threadIdx.x;            // 128 threads
  int b = tid >> 6, co = tid & 63;
  float inv = 1.f / (float)HWp;
  float hid[4];
  #pragma unroll
  for (int j = 0; j < 4; j++) {
    float acc = bd[j];
    for (int c = 0; c < 64; c++) acc += wd[j*64+c] * (sums[b*64+c] * inv);
    hid[j] = fmaxf(acc, 0.f);
  }
  float acc = bu[co];
  #pragma unroll
  for (int j = 0; j < 4; j++) acc += wu[co*4+j] * hid[j];
  att[tid] = 1.f / (1.f + __expf(-acc));
}

// ------------------- K9: final combine + NHWC -> NCHW -------------------
__global__ __launch_bounds__(256) void k_final(
    const float* __restrict__ x1, const float* __restrict__ c2,
    const float* __restrict__ skip2, const float* __restrict__ att,
    float* __restrict__ out){
  __shared__ float t[64][65];
  int b = blockIdx.x / WPB;
  int hw0 = (blockIdx.x % WPB) * 64;
  int lane = threadIdx.x & 63, grp = threadIdx.x >> 6;
  float sk = skip2[lane], at = att[b*64 + lane];
  #pragma unroll
  for (int r = 0; r < 64; r += 4) {
    int hwl = r + grp;
    size_t T = (size_t)b*HWp + hw0 + hwl;
    t[hwl][lane] = x1[T*64+lane]*sk + c2[T*64+lane]*at;
  }
  __syncthreads();
  float* ob = out + (size_t)b * Cch * HWp;
  #pragma unroll
  for (int r = 0; r < 64; r += 4) {
    int c = r + grp;
    ob[(size_t)c*HWp + hw0 + lane] = t[lane][c];
  }
}

extern "C" void kernel_launch(void* const* d_in, const int* in_sizes, int n_in,
                              void* d_out, int out_size, void* d_ws, size_t ws_size,
                              hipStream_t stream) {
  (void)in_sizes; (void)n_in; (void)out_size; (void)ws_size;
  const float* x      = (const float*)d_in[0];
  const float* ln1_g  = (const float*)d_in[1];
  const float* ln1_b  = (const float*)d_in[2];
  const float* in_w   = (const float*)d_in[3];
  const float* in_b   = (const float*)d_in[4];
  const float* conv_w = (const float*)d_in[5];
  const float* conv_b = (const float*)d_in[6];
  const float* xproj_w= (const float*)d_in[7];
  const float* dt_w   = (const float*)d_in[8];
  const float* dt_b   = (const float*)d_in[9];
  const float* A_log  = (const float*)d_in[10];
  const float* Dp     = (const float*)d_in[11];
  const float* out_w  = (const float*)d_in[12];
  const float* out_b  = (const float*)d_in[13];
  const float* skip1  = (const float*)d_in[14];
  const float* ln2_g  = (const float*)d_in[15];
  const float* ln2_b  = (const float*)d_in[16];
  const float* skip2  = (const float*)d_in[17];
  const float* cab_w1 = (const float*)d_in[18];
  const float* cab_b1 = (const float*)d_in[19];
  const float* cab_w2 = (const float*)d_in[20];
  const float* cab_b2 = (const float*)d_in[21];
  const float* ca_wd  = (const float*)d_in[22];
  const float* ca_bd  = (const float*)d_in[23];
  const float* ca_wu  = (const float*)d_in[24];
  const float* ca_bu  = (const float*)d_in[25];

  float* ws   = (float*)d_ws;
  float* xT   = ws;                        // [0, 4718592)
  float* xc   = ws + 4718592;              // [4718592, 14155776)  g in-place; c2 aliases later
  float* z    = ws + 14155776;             // [14155776, 23592960) x1/x2 alias later
  float* dbc  = ws + 23592960;             // [23592960, 26247168) c1 aliases later
  float* sums = ws + 26247168;             // 128
  float* att  = ws + 26247296;             // 128
  float* x1   = ws + 14155776;             // alias over z (z dead after k_scan2)
  float* x2   = ws + 18874368;             // alias over z second half
  float* c1   = ws + 23592960;             // alias over dbc (dead after k_scan2)
  float* c2   = ws + 4718592;              // alias over xc/g (dead after k_out)

  hipMemsetAsync(sums, 0, 128*sizeof(float), stream);
  k_transpose<<<NW, 256, 0, stream>>>(x, xT);
  k_stage1<<<NW, 256, 0, stream>>>(xT, ln1_g, ln1_b, in_w, in_b, conv_w, conv_b, xc, z);
  k_dbc<<<NW, 256, 0, stream>>>(xc, xproj_w, dbc);
  k_scan2<<<NW, 128, 0, stream>>>(xc, z, dbc, dt_w, dt_b, A_log, Dp);
  k_out<<<NW, 256, 0, stream>>>(xT, xc, out_w, out_b, skip1, ln2_g, ln2_b, x1, x2);
  k_conv1<<<NW, 256, 0, stream>>>(x2, cab_w1, cab_b1, c1);
  k_conv2<<<NW, 256, 0, stream>>>(c1, cab_w2, cab_b2, c2, sums);
  k_att<<<1, 128, 0, stream>>>(sums, ca_wd, ca_bd, ca_wu, ca_bu, att);
  k_final<<<NW, 256, 0, stream>>>(x1, c2, skip2, att, (float*)d_out);
}